// Round 13
// baseline (58.791 us; speedup 1.0000x reference)
//
#include <hip/hip_runtime.h>
#include <hip/hip_bf16.h>

// KPConv fused kernel for MI355X (gfx950) — round 13.
// B=4, M=16384, K_NB=32, D_IN=64, D_OUT=64, K_PTS=15, SIGMA=1.
//
// R13 vs R12 (R12 = 47.6 us kernel):
//  * h computed upfront for all 8 points (ah[8] in regs); per-neighbor activity
//    bit = ballot(d2<1) over the 16 kernel-point lanes. Inactive neighbors
//    (~half: r ~ N(0,2I) vs unit balls at Q) gather from a fixed L1-hot dummy
//    row via one v_cndmask on the address -> F-gather transactions ~halve.
//    Exact: inactive => all h == 0 => B operand irrelevant (finite garbage).
//  * W fragments for first 4 K-steps prefetched before __syncthreads.
//  * Everything else = R12 verified: XP packed X, idxs in LDS, fused-32
//    stage-2 with shared W load, fk 64 KB + stg aliased row heads, kappa
//    layout, all swizzles, XCD mapping.

#define BATCH 4
#define MPTS  16384
#define KNB   32
#define DIN   64
#define DOUT  64
#define KP    15
#define K2P   1024          // padded K: kappa = n*64 + (p>>2)*16 + t*4 + (p&3), d = 4n+t
#define KSTEPS (K2P/32)     // 32
#define ROWB  (K2P*2)       // 2048 bytes per fk row
#define PTS   (BATCH*MPTS)  // 65536
#define PPB   32            // points per block (one fused 32-row tile)
#define NBLK  (PTS/PPB)     // 2048
#define WBELEMS (K2P*DOUT)  // 65536 ushorts = 131072 B
#define WBBLK (WBELEMS/256)     // 256 prep blocks
#define FBBLK (PTS*DIN/8/256)   // 2048 prep blocks
#define XPBLK (PTS/256)         // 256 prep blocks
#define FBOFF 131072                  // byte offsets in ws
#define XPOFF (FBOFF + PTS*DIN*2)     // 8519680
#define WSNEED (XPOFF + PTS*16)       // 9568256

typedef __bf16 bf16x8 __attribute__((ext_vector_type(8)));
typedef float  f32x4  __attribute__((ext_vector_type(4)));
typedef unsigned short u16x8 __attribute__((ext_vector_type(8)));

static __device__ __forceinline__ unsigned short f2b(float x) {
    __bf16 h = (__bf16)x;              // RNE convert
    return __builtin_bit_cast(unsigned short, h);
}

// ---- merged prep: WB fragments | F f32->bf16 | X -> float4 pack ----
__global__ void prep_all(const float* __restrict__ W, const float* __restrict__ F,
                         const float* __restrict__ X,
                         unsigned short* __restrict__ wb, unsigned short* __restrict__ fb,
                         float4* __restrict__ xp, int do_xp) {
    int bid = blockIdx.x;
    if (bid < WBBLK) {
        int idx = bid * 256 + threadIdx.x;
        int i    = idx & 7;
        int lane = (idx >> 3) & 63;
        int ks   = (idx >> 9) & 31;
        int et   = idx >> 14;
        int kap  = ks * 32 + ((lane >> 4) << 3) + i;
        int n = kap >> 6;
        int g = (kap >> 4) & 3;
        int t = (kap >> 2) & 3;
        int r = kap & 3;
        int p = g * 4 + r;
        int d = n * 4 + t;
        int e = et * 16 + (lane & 15);
        float v = (p < KP) ? W[(p * DIN + d) * DOUT + e] : 0.f;
        wb[idx] = f2b(v);
    } else if (bid < WBBLK + FBBLK) {
        int i = (bid - WBBLK) * 256 + threadIdx.x;    // exactly PTS*DIN/8 threads
        const float4* s = reinterpret_cast<const float4*>(F) + (size_t)i * 2;
        float4 a = s[0], b = s[1];
        u16x8 o;
        o[0] = f2b(a.x); o[1] = f2b(a.y); o[2] = f2b(a.z); o[3] = f2b(a.w);
        o[4] = f2b(b.x); o[5] = f2b(b.y); o[6] = f2b(b.z); o[7] = f2b(b.w);
        *(reinterpret_cast<u16x8*>(fb) + i) = o;
    } else if (do_xp) {
        int row = (bid - WBBLK - FBBLK) * 256 + threadIdx.x;   // exactly PTS threads
        const float* x = X + (size_t)row * 3;
        xp[row] = make_float4(x[0], x[1], x[2], 0.f);
    }
}

template<bool UXP>
__global__ __launch_bounds__(256, 2)
void kpconv_main(const float* __restrict__ X, const float4* __restrict__ XP,
                 const unsigned short* __restrict__ FB,
                 const int* __restrict__ NB, const float* __restrict__ Q,
                 const unsigned short* __restrict__ WB, float* __restrict__ OUT) {
    // 64 KB fk (32 rows x 2048 B); wave wv's stg for point j (float4[32],
    // slot-swizzled) aliases the first 512 B of fk row wv*8+j. All stg reads
    // now happen in the upfront-h phase, before any fk-row write (same wave).
    __shared__ unsigned short fk[PPB * K2P];
    __shared__ int idxs[4][8][KNB];     // 4 KB: per-wave neighbor gidx
    char* const fkb = reinterpret_cast<char*>(fk);

    const int tid  = threadIdx.x;
    const int wv   = tid >> 6;    // wave 0..3
    const int lane = tid & 63;
    const int g16  = lane >> 4;   // 0..3
    const int r16  = lane & 15;   // 0..15

    // per-lane kernel-point constants; p=15 pad row gets far-away virtual point -> h=0
    float qx = 1.0e3f, qy = 0.f, qz = 0.f;
    if (r16 < KP) { qx = Q[r16 * 3 + 0]; qy = Q[r16 * 3 + 1]; qz = Q[r16 * 3 + 2]; }
    const float qq   = qx * qx + qy * qy + qz * qz;
    const float nq2x = -2.f * qx, nq2y = -2.f * qy, nq2z = -2.f * qz;

    // XCD-aware mapping: XCD (bid&7) owns one batch's 8192-point span
    const int bid     = blockIdx.x;
    const int base_pt = (bid & 7) * (PTS / 8) + (bid >> 3) * PPB;
    const int boff    = (base_pt >> 14) * MPTS;   // uniform per block
    const int pid0    = base_pt + wv * 8;         // this wave's 8 points

    // ---- staging: r-vectors into fk-row heads (slot-swizzled) + gidx into idxs ----
    #pragma unroll
    for (int e = 0; e < 4; ++e) {
        int ent = lane + e * 64;          // 0..255 = 8 pts x 32 nb
        int j = ent >> 5, k = ent & 31;
        int pid = pid0 + j;
        int nb  = NB[(size_t)pid * KNB + k];
        int gidx = boff + nb;
        float rx, ry, rz;
        if constexpr (UXP) {
            float4 xn = XP[gidx];
            float4 xc = XP[pid];          // broadcast within the 32-lane point group
            rx = xn.x - xc.x; ry = xn.y - xc.y; rz = xn.z - xc.z;
        } else {
            const float* xn = X + (size_t)gidx * 3;
            const float* xc = X + (size_t)pid * 3;
            rx = xn[0] - xc[0]; ry = xn[1] - xc[1]; rz = xn[2] - xc[2];
        }
        float rr = fmaf(rx, rx, fmaf(ry, ry, rz * rz));
        int slot = (k & 24) | ((k ^ (k >> 3)) & 7);
        *reinterpret_cast<float4*>(fkb + (wv * 8 + j) * ROWB + slot * 16) =
            make_float4(rx, ry, rz, rr);   // same-wave produce/consume
        idxs[wv][j][k] = gidx;             // linear -> conflict-free write
    }

    // ---- upfront h phase: A fragments + per-neighbor activity masks ----
    // ah[j][i] = h(p=r16, k=g16*8+i) for point j; act[j] bit i = any lane in
    // this 16-lane group has d2<1 for neighbor g16*8+i (else all h == 0).
    bf16x8 ah[8];
    int    act[8];
    #pragma unroll
    for (int j = 0; j < 8; ++j) {
        const int row = wv * 8 + j;
        bf16x8 a;
        int am = 0;
        #pragma unroll
        for (int i = 0; i < 8; ++i) {
            float4 rv = *reinterpret_cast<const float4*>(
                fkb + row * ROWB + (g16 * 8 + (i ^ g16)) * 16);
            float d2 = fmaf(rv.x, nq2x, fmaf(rv.y, nq2y, fmaf(rv.z, nq2z, rv.w + qq)));
            unsigned long long m = __ballot(d2 < 1.0f);
            unsigned grp = (unsigned)(m >> (g16 * 16)) & 0xffffu;
            am |= (grp ? 1 : 0) << i;
            d2 = fmaxf(d2, 0.f);
            a[i] = (__bf16)fmaxf(1.f - __builtin_amdgcn_sqrtf(d2), 0.f);
        }
        ah[j]  = a;
        act[j] = am;
    }

    // ---- 2-ahead pipelined F gathers; inactive neighbors -> L1-hot dummy row ----
    union U { uint2 d; unsigned short s[4]; };
    U L[2][8];

    auto issue_gather = [&](int j, U* Lj, int am) {
        const int4* ip = reinterpret_cast<const int4*>(&idxs[wv][j][g16 * 8]);
        int4 a = ip[0];
        int4 b = ip[1];
        int g[8] = {a.x, a.y, a.z, a.w, b.x, b.y, b.z, b.w};
        #pragma unroll
        for (int i = 0; i < 8; ++i) {
            int gi = ((am >> i) & 1) ? g[i] : boff;   // one v_cndmask per neighbor
            Lj[i].d = *reinterpret_cast<const uint2*>(
                FB + ((size_t)gi << 6) + (r16 << 2));
        }
    };

    issue_gather(0, L[0], act[0]);
    issue_gather(1, L[1], act[1]);

    // ---------------- stage 1: 8 points per wave, 2-ahead pipelined ----------------
    #pragma unroll
    for (int j = 0; j < 8; ++j) {
        const int row = wv * 8 + j;                // fk row (0..31)

        // extract B fragments from this j's gather buffer, then reuse it for j+2
        bf16x8 bfr[4];
        #pragma unroll
        for (int t = 0; t < 4; ++t)
            #pragma unroll
            for (int i = 0; i < 8; ++i)
                bfr[t][i] = __builtin_bit_cast(__bf16, L[j & 1][i].s[t]);

        if (j < 6) issue_gather(j + 2, L[j & 1], act[j + 2]);

        const f32x4 z = {0.f, 0.f, 0.f, 0.f};
        f32x4 accs[4];
        #pragma unroll
        for (int t = 0; t < 4; ++t)
            accs[t] = __builtin_amdgcn_mfma_f32_16x16x32_bf16(ah[j], bfr[t], z, 0, 0, 0);

        // fk write: lane holds kappa r16*64+g16*16..+15 (32 B) -> 2x ds_write_b128
        bf16x8 w0, w1;
        #pragma unroll
        for (int r = 0; r < 4; ++r) {
            w0[r]     = (__bf16)accs[0][r];
            w0[4 + r] = (__bf16)accs[1][r];
            w1[r]     = (__bf16)accs[2][r];
            w1[4 + r] = (__bf16)accs[3][r];
        }
        int swz  = (row & 7) ^ (r16 & 7);
        int off0 = row * ROWB + (r16 * 8 + ((g16 * 2 + 0) ^ swz)) * 16;
        int off1 = row * ROWB + (r16 * 8 + ((g16 * 2 + 1) ^ swz)) * 16;
        *reinterpret_cast<bf16x8*>(fkb + off0) = w0;
        *reinterpret_cast<bf16x8*>(fkb + off1) = w1;
    }

    // ---- W prefetch for first 4 K-steps (issues before the barrier drain) ----
    const unsigned short* wbp = WB + ((size_t)(wv * KSTEPS) * 64 + lane) * 8;
    asm volatile("" : "+v"(wbp));   // defeat LICM for the streamed remainder
    bf16x8 bpre[4];
    #pragma unroll
    for (int t = 0; t < 4; ++t)
        bpre[t] = *reinterpret_cast<const bf16x8*>(wbp + t * 512);

    __syncthreads();   // all 32 fk rows visible to all waves

    // ------- stage 2 (fused): [32 x 1024] x [1024 x 16] per wave -------
    f32x4 o0 = {0.f, 0.f, 0.f, 0.f};
    f32x4 o1 = {0.f, 0.f, 0.f, 0.f};
    #pragma unroll
    for (int ks = 0; ks < KSTEPS; ++ks) {
        bf16x8 b = (ks < 4) ? bpre[ks]
                            : *reinterpret_cast<const bf16x8*>(wbp + ks * 512);
        int stored = (ks * 4 + g16) ^ (r16 & 7) ^ ((ks >> 1) & 7);
        bf16x8 a0 = *reinterpret_cast<const bf16x8*>(fkb + r16 * ROWB + stored * 16);
        bf16x8 a1 = *reinterpret_cast<const bf16x8*>(fkb + (16 + r16) * ROWB + stored * 16);
        o0 = __builtin_amdgcn_mfma_f32_16x16x32_bf16(a0, b, o0, 0, 0, 0);
        o1 = __builtin_amdgcn_mfma_f32_16x16x32_bf16(a1, b, o1, 0, 0, 0);
    }

    #pragma unroll
    for (int r = 0; r < 4; ++r) {
        int p0 = base_pt + g16 * 4 + r;
        OUT[(size_t)p0 * DOUT + wv * 16 + r16] = o0[r];
        int p1 = base_pt + 16 + g16 * 4 + r;
        OUT[(size_t)p1 * DOUT + wv * 16 + r16] = o1[r];
    }
}

extern "C" void kernel_launch(void* const* d_in, const int* in_sizes, int n_in,
                              void* d_out, int out_size, void* d_ws, size_t ws_size,
                              hipStream_t stream) {
    const float* X = (const float*)d_in[0];
    const float* F = (const float*)d_in[1];
    const int*   N = (const int*)d_in[2];
    const float* Q = (const float*)d_in[3];
    const float* W = (const float*)d_in[4];
    float* OUT = (float*)d_out;
    unsigned short* WB = (unsigned short*)d_ws;                       // [0, 131072)
    unsigned short* FB = (unsigned short*)((char*)d_ws + FBOFF);      // 8 MB
    float4*         XP = (float4*)((char*)d_ws + XPOFF);              // 1 MB

    const int use_xp = (ws_size >= (size_t)WSNEED) ? 1 : 0;

    prep_all<<<WBBLK + FBBLK + (use_xp ? XPBLK : 0), 256, 0, stream>>>(
        W, F, X, WB, FB, XP, use_xp);

    if (use_xp)
        kpconv_main<true><<<NBLK, 256, 0, stream>>>(X, XP, FB, N, Q, WB, OUT);
    else
        kpconv_main<false><<<NBLK, 256, 0, stream>>>(X, XP, FB, N, Q, WB, OUT);
}

// Round 14
// 55.023 us; speedup vs baseline: 1.0685x; 1.0685x over previous
//
#include <hip/hip_runtime.h>
#include <hip/hip_bf16.h>

// KPConv fused kernel for MI355X (gfx950) — round 14 = exact revert to R12,
// the best verified configuration (47.6-48.8 us kernel).
// B=4, M=16384, K_NB=32, D_IN=64, D_OUT=64, K_PTS=15, SIGMA=1.
//
// R13's masked-gather regressed (+4-5 us): v_cndmask swaps addresses but not
// per-lane TA requests, and ballot added VALU. Reverted per pre-commit.
//
// Verified structure:
//  * XP: X pre-packed into float4 rows (1 MB ws) -> xn staging is ONE 16B
//    request; xc is a broadcast.
//  * NB int4 gather loads deleted: gidx staged once into a 4 KB idxs LDS
//    array; gather pipeline reads it back broadcast (zero TA requests).
//  * PPB=32 fused stage-2: one W load per K-step feeds rows 0-15 and 16-31.
//  * fk 64 KB with stg aliased into row heads; kappa = n*64+(p>>2)*16+t*4+(p&3);
//    fk chunk swizzle c^(row&7)^((c>>3)&7); stg slot swizzle; XCD mapping.

#define BATCH 4
#define MPTS  16384
#define KNB   32
#define DIN   64
#define DOUT  64
#define KP    15
#define K2P   1024          // padded K: kappa = n*64 + (p>>2)*16 + t*4 + (p&3), d = 4n+t
#define KSTEPS (K2P/32)     // 32
#define ROWB  (K2P*2)       // 2048 bytes per fk row
#define PTS   (BATCH*MPTS)  // 65536
#define PPB   32            // points per block (one fused 32-row tile)
#define NBLK  (PTS/PPB)     // 2048
#define WBELEMS (K2P*DOUT)  // 65536 ushorts = 131072 B
#define WBBLK (WBELEMS/256)     // 256 prep blocks
#define FBBLK (PTS*DIN/8/256)   // 2048 prep blocks
#define XPBLK (PTS/256)         // 256 prep blocks
#define FBOFF 131072                  // byte offsets in ws
#define XPOFF (FBOFF + PTS*DIN*2)     // 8519680
#define WSNEED (XPOFF + PTS*16)       // 9568256

typedef __bf16 bf16x8 __attribute__((ext_vector_type(8)));
typedef float  f32x4  __attribute__((ext_vector_type(4)));
typedef unsigned short u16x8 __attribute__((ext_vector_type(8)));

static __device__ __forceinline__ unsigned short f2b(float x) {
    __bf16 h = (__bf16)x;              // RNE convert
    return __builtin_bit_cast(unsigned short, h);
}

// ---- merged prep: WB fragments | F f32->bf16 | X -> float4 pack ----
__global__ void prep_all(const float* __restrict__ W, const float* __restrict__ F,
                         const float* __restrict__ X,
                         unsigned short* __restrict__ wb, unsigned short* __restrict__ fb,
                         float4* __restrict__ xp, int do_xp) {
    int bid = blockIdx.x;
    if (bid < WBBLK) {
        int idx = bid * 256 + threadIdx.x;
        int i    = idx & 7;
        int lane = (idx >> 3) & 63;
        int ks   = (idx >> 9) & 31;
        int et   = idx >> 14;
        int kap  = ks * 32 + ((lane >> 4) << 3) + i;
        int n = kap >> 6;
        int g = (kap >> 4) & 3;
        int t = (kap >> 2) & 3;
        int r = kap & 3;
        int p = g * 4 + r;
        int d = n * 4 + t;
        int e = et * 16 + (lane & 15);
        float v = (p < KP) ? W[(p * DIN + d) * DOUT + e] : 0.f;
        wb[idx] = f2b(v);
    } else if (bid < WBBLK + FBBLK) {
        int i = (bid - WBBLK) * 256 + threadIdx.x;    // exactly PTS*DIN/8 threads
        const float4* s = reinterpret_cast<const float4*>(F) + (size_t)i * 2;
        float4 a = s[0], b = s[1];
        u16x8 o;
        o[0] = f2b(a.x); o[1] = f2b(a.y); o[2] = f2b(a.z); o[3] = f2b(a.w);
        o[4] = f2b(b.x); o[5] = f2b(b.y); o[6] = f2b(b.z); o[7] = f2b(b.w);
        *(reinterpret_cast<u16x8*>(fb) + i) = o;
    } else if (do_xp) {
        int row = (bid - WBBLK - FBBLK) * 256 + threadIdx.x;   // exactly PTS threads
        const float* x = X + (size_t)row * 3;
        xp[row] = make_float4(x[0], x[1], x[2], 0.f);
    }
}

template<bool UXP>
__global__ __launch_bounds__(256, 2)
void kpconv_main(const float* __restrict__ X, const float4* __restrict__ XP,
                 const unsigned short* __restrict__ FB,
                 const int* __restrict__ NB, const float* __restrict__ Q,
                 const unsigned short* __restrict__ WB, float* __restrict__ OUT) {
    // 64 KB fk (32 rows x 2048 B); wave wv's stg for point j (float4[32],
    // slot-swizzled) aliases the first 512 B of fk row wv*8+j (R8-verified:
    // consumed in iteration j before that row's fk write, same wave, in-order).
    __shared__ unsigned short fk[PPB * K2P];
    __shared__ int idxs[4][8][KNB];     // 4 KB: per-wave neighbor gidx
    char* const fkb = reinterpret_cast<char*>(fk);

    const int tid  = threadIdx.x;
    const int wv   = tid >> 6;    // wave 0..3
    const int lane = tid & 63;
    const int g16  = lane >> 4;   // 0..3
    const int r16  = lane & 15;   // 0..15

    // per-lane kernel-point constants; p=15 pad row gets far-away virtual point -> h=0
    float qx = 1.0e3f, qy = 0.f, qz = 0.f;
    if (r16 < KP) { qx = Q[r16 * 3 + 0]; qy = Q[r16 * 3 + 1]; qz = Q[r16 * 3 + 2]; }
    const float qq   = qx * qx + qy * qy + qz * qz;
    const float nq2x = -2.f * qx, nq2y = -2.f * qy, nq2z = -2.f * qz;

    // XCD-aware mapping: XCD (bid&7) owns one batch's 8192-point span
    const int bid     = blockIdx.x;
    const int base_pt = (bid & 7) * (PTS / 8) + (bid >> 3) * PPB;
    const int boff    = (base_pt >> 14) * MPTS;   // uniform per block
    const int pid0    = base_pt + wv * 8;         // this wave's 8 points

    // ---- staging: r-vectors into fk-row heads (slot-swizzled) + gidx into idxs ----
    #pragma unroll
    for (int e = 0; e < 4; ++e) {
        int ent = lane + e * 64;          // 0..255 = 8 pts x 32 nb
        int j = ent >> 5, k = ent & 31;
        int pid = pid0 + j;
        int nb  = NB[(size_t)pid * KNB + k];
        int gidx = boff + nb;
        float rx, ry, rz;
        if constexpr (UXP) {
            float4 xn = XP[gidx];
            float4 xc = XP[pid];          // broadcast within the 32-lane point group
            rx = xn.x - xc.x; ry = xn.y - xc.y; rz = xn.z - xc.z;
        } else {
            const float* xn = X + (size_t)gidx * 3;
            const float* xc = X + (size_t)pid * 3;
            rx = xn[0] - xc[0]; ry = xn[1] - xc[1]; rz = xn[2] - xc[2];
        }
        float rr = fmaf(rx, rx, fmaf(ry, ry, rz * rz));
        int slot = (k & 24) | ((k ^ (k >> 3)) & 7);
        *reinterpret_cast<float4*>(fkb + (wv * 8 + j) * ROWB + slot * 16) =
            make_float4(rx, ry, rz, rr);   // same-wave produce/consume
        idxs[wv][j][k] = gidx;             // linear -> conflict-free write
    }

    // ---- 2-ahead pipelined F gathers; gidx from idxs (LDS, broadcast reads) ----
    union U { uint2 d; unsigned short s[4]; };
    U L[2][8];

    auto issue_gather = [&](int j, U* Lj) {
        // lane needs idxs[wv][j][g16*8 .. +7] = 32 B (broadcast within 16-lane group)
        const int4* ip = reinterpret_cast<const int4*>(&idxs[wv][j][g16 * 8]);
        int4 a = ip[0];
        int4 b = ip[1];
        int g[8] = {a.x, a.y, a.z, a.w, b.x, b.y, b.z, b.w};
        #pragma unroll
        for (int i = 0; i < 8; ++i)
            Lj[i].d = *reinterpret_cast<const uint2*>(
                FB + ((size_t)g[i] << 6) + (r16 << 2));
    };

    issue_gather(0, L[0]);
    issue_gather(1, L[1]);

    // ---------------- stage 1: 8 points per wave, 2-ahead pipelined ----------------
    #pragma unroll
    for (int j = 0; j < 8; ++j) {
        const int row = wv * 8 + j;                // fk row (0..31)

        // A fragment: h(p=r16, k=g16*8+i), dot-form d^2 clamped to 0
        bf16x8 ah;
        #pragma unroll
        for (int i = 0; i < 8; ++i) {
            float4 rv = *reinterpret_cast<const float4*>(
                fkb + row * ROWB + (g16 * 8 + (i ^ g16)) * 16);
            float d2 = fmaf(rv.x, nq2x, fmaf(rv.y, nq2y, fmaf(rv.z, nq2z, rv.w + qq)));
            d2 = fmaxf(d2, 0.f);
            ah[i] = (__bf16)fmaxf(1.f - __builtin_amdgcn_sqrtf(d2), 0.f);
        }

        // extract B fragments from this j's gather buffer, then reuse it for j+2
        bf16x8 bfr[4];
        #pragma unroll
        for (int t = 0; t < 4; ++t)
            #pragma unroll
            for (int i = 0; i < 8; ++i)
                bfr[t][i] = __builtin_bit_cast(__bf16, L[j & 1][i].s[t]);

        if (j < 6) issue_gather(j + 2, L[j & 1]);

        const f32x4 z = {0.f, 0.f, 0.f, 0.f};
        f32x4 accs[4];
        #pragma unroll
        for (int t = 0; t < 4; ++t)
            accs[t] = __builtin_amdgcn_mfma_f32_16x16x32_bf16(ah, bfr[t], z, 0, 0, 0);

        // fk write: lane holds kappa r16*64+g16*16..+15 (32 B) -> 2x ds_write_b128
        // (overwrites this row's stg head only AFTER all its reads above)
        bf16x8 w0, w1;
        #pragma unroll
        for (int r = 0; r < 4; ++r) {
            w0[r]     = (__bf16)accs[0][r];
            w0[4 + r] = (__bf16)accs[1][r];
            w1[r]     = (__bf16)accs[2][r];
            w1[4 + r] = (__bf16)accs[3][r];
        }
        int swz  = (row & 7) ^ (r16 & 7);
        int off0 = row * ROWB + (r16 * 8 + ((g16 * 2 + 0) ^ swz)) * 16;
        int off1 = row * ROWB + (r16 * 8 + ((g16 * 2 + 1) ^ swz)) * 16;
        *reinterpret_cast<bf16x8*>(fkb + off0) = w0;
        *reinterpret_cast<bf16x8*>(fkb + off1) = w1;
    }

    __syncthreads();   // all 32 fk rows visible to all waves

    // ------- stage 2 (fused): [32 x 1024] x [1024 x 16] per wave -------
    // One W load per K-step feeds both row-halves (R11-verified).
    const unsigned short* wbp = WB + ((size_t)(wv * KSTEPS) * 64 + lane) * 8;
    asm volatile("" : "+v"(wbp));   // defeat LICM: stream W from L1/L2, not 128 regs

    f32x4 o0 = {0.f, 0.f, 0.f, 0.f};
    f32x4 o1 = {0.f, 0.f, 0.f, 0.f};
    #pragma unroll
    for (int ks = 0; ks < KSTEPS; ++ks) {
        bf16x8 b = *reinterpret_cast<const bf16x8*>(wbp + ks * 512);
        int stored = (ks * 4 + g16) ^ (r16 & 7) ^ ((ks >> 1) & 7);
        bf16x8 a0 = *reinterpret_cast<const bf16x8*>(fkb + r16 * ROWB + stored * 16);
        bf16x8 a1 = *reinterpret_cast<const bf16x8*>(fkb + (16 + r16) * ROWB + stored * 16);
        o0 = __builtin_amdgcn_mfma_f32_16x16x32_bf16(a0, b, o0, 0, 0, 0);
        o1 = __builtin_amdgcn_mfma_f32_16x16x32_bf16(a1, b, o1, 0, 0, 0);
    }

    #pragma unroll
    for (int r = 0; r < 4; ++r) {
        int p0 = base_pt + g16 * 4 + r;
        OUT[(size_t)p0 * DOUT + wv * 16 + r16] = o0[r];
        int p1 = base_pt + 16 + g16 * 4 + r;
        OUT[(size_t)p1 * DOUT + wv * 16 + r16] = o1[r];
    }
}

extern "C" void kernel_launch(void* const* d_in, const int* in_sizes, int n_in,
                              void* d_out, int out_size, void* d_ws, size_t ws_size,
                              hipStream_t stream) {
    const float* X = (const float*)d_in[0];
    const float* F = (const float*)d_in[1];
    const int*   N = (const int*)d_in[2];
    const float* Q = (const float*)d_in[3];
    const float* W = (const float*)d_in[4];
    float* OUT = (float*)d_out;
    unsigned short* WB = (unsigned short*)d_ws;                       // [0, 131072)
    unsigned short* FB = (unsigned short*)((char*)d_ws + FBOFF);      // 8 MB
    float4*         XP = (float4*)((char*)d_ws + XPOFF);              // 1 MB

    const int use_xp = (ws_size >= (size_t)WSNEED) ? 1 : 0;

    prep_all<<<WBBLK + FBBLK + (use_xp ? XPBLK : 0), 256, 0, stream>>>(
        W, F, X, WB, FB, XP, use_xp);

    if (use_xp)
        kpconv_main<true><<<NBLK, 256, 0, stream>>>(X, XP, FB, N, Q, WB, OUT);
    else
        kpconv_main<false><<<NBLK, 256, 0, stream>>>(X, XP, FB, N, Q, WB, OUT);
}